// Round 1
// baseline (462.761 us; speedup 1.0000x reference)
//
#include <hip/hip_runtime.h>
#include <math.h>

// Relational Network fused pipeline for MI355X (gfx950).
// B=32, D=64, K=26, QST=256, G=[512x6, 28], AGG at layer 4.
//
// Round 6 changes vs round 5:
//  - k_uv eliminated: layer 0 is computed inside k_fused as a 2-step MFMA
//    over K=64 (x-pair tile padded with zeros), W0 packed to bf16 like W1-3.
//    Removes one launch + U/V workspace + the heavy 16-iter staging prologue
//    (which was a big part of the register spill: 108 B/thread scratch).
//  - Layers 1..3 inner loop software-pipelined 2-deep on the L2 weight
//    stream (ping-pong bA/bB), A-fragments loaded in mt-pairs between
//    8-MFMA clusters, s_setprio(1) around clusters. Live set ~115 regs
//    (< 128 unified cap at launch_bounds(512,4)) -> no scratch.
//  - Epilogue packs (col,col+1) bf16 pairs via DPP quad_perm (VALU) and
//    writes ds_write_b32 from even lanes only: 64 u16 -> 32 b32 stores,
//    2-way bank pattern (free) instead of 4-way + same-dword serialization.

typedef __attribute__((ext_vector_type(8))) short bf16x8;   // 8 bf16 in 4 VGPRs
typedef __attribute__((ext_vector_type(4))) float f32x4;    // MFMA 16x16 accumulator
typedef __attribute__((ext_vector_type(4))) unsigned int u32x4;

__device__ __forceinline__ unsigned short f2bf(float f) {
    union { float f; unsigned u; } x; x.f = f;
    unsigned r = x.u + 0x7fffu + ((x.u >> 16) & 1u);   // RNE
    return (unsigned short)(r >> 16);
}

// ---------------- pack / transpose weights (+ zero S) ----------------
// Wp layout per layer: [wave(8)][s(16)][jj(4)][lane(64)][j(8)] bf16,
//   value = W[n][k], n = (wave*4+jj)*16 + (lane&15), k = s*32 + (lane>>4)*8 + j.
// W0p: same layout with s(2), k = s*32 + (lane>>4)*8 + j over padded K=64
//   (k >= 52 -> 0).
#define NP_WP   786432            // 3 * 512*512
#define NP_W0P  32768             // 512*64 (K padded 52->64)
#define NP_W4T  393216            // 512*768
#define NP_W5T  262144            // 512*512
#define NP_S    16384             // 32*512
#define NP_TOTAL (NP_WP + NP_W0P + NP_W4T + NP_W5T + NP_S)
__global__ void k_prep(const float* __restrict__ W1, const float* __restrict__ W2,
                       const float* __restrict__ W3, const float* __restrict__ W0,
                       const float* __restrict__ W4, const float* __restrict__ W5,
                       unsigned short* __restrict__ Wp,   // [3][262144] bf16
                       unsigned short* __restrict__ W0p,  // [32768] bf16
                       float* __restrict__ W4t,           // [768][512] fp32
                       float* __restrict__ W5t,           // [512][512] fp32
                       float* __restrict__ S)             // [32][512] fp32 (zeroed)
{
    int f = blockIdx.x * 256 + threadIdx.x;
    if (f < NP_WP) {
        int l = f >> 18, r = f & 262143;
        int n = r >> 9, k = r & 511;                    // read W[n*512+k] coalesced
        const float* W = (l == 0) ? W1 : (l == 1) ? W2 : W3;
        float v = W[r];
        int wv = n >> 6, jj = (n >> 4) & 3, i16 = n & 15;
        int s = k >> 5, q4 = (k >> 3) & 3, j = k & 7;
        int lane = q4 * 16 + i16;
        Wp[(size_t)l * 262144 + ((((wv * 16 + s) * 4 + jj) * 64 + lane) << 3) + j] = f2bf(v);
    } else if (f < NP_WP + NP_W0P) {
        int g = f - NP_WP;
        int n = g >> 6, k = g & 63;
        float v = (k < 52) ? W0[n * 52 + k] : 0.f;
        int wv = n >> 6, jj = (n >> 4) & 3, i16 = n & 15;
        int s = k >> 5, q4 = (k >> 3) & 3, j = k & 7;
        int lane = q4 * 16 + i16;
        W0p[((((wv * 2 + s) * 4 + jj) * 64 + lane) << 3) + j] = f2bf(v);
    } else if (f < NP_WP + NP_W0P + NP_W4T) {
        int g = f - (NP_WP + NP_W0P);
        int o = g / 768, k = g % 768;                   // read W4[g] coalesced
        W4t[k * 512 + o] = W4[g];
    } else if (f < NP_WP + NP_W0P + NP_W4T + NP_W5T) {
        int g = f - (NP_WP + NP_W0P + NP_W4T);
        int o = g >> 9, k = g & 511;                    // read W5[g] coalesced
        W5t[k * 512 + o] = W5[g];
    } else if (f < NP_TOTAL) {
        S[f - (NP_WP + NP_W0P + NP_W4T + NP_W5T)] = 0.f;
    }
}

// ---------------- h-store epilogue: bias + relu + swizzled bf16 LDS write ----
// Packs (col, col+1) into one dword via DPP quad_perm lane swap; even lanes
// write ds_write_b32. Swizzle matches the A-read: granule (col>>3)^(row&7).
__device__ __forceinline__ void store_h(const f32x4 (&acc)[4][4], const float* __restrict__ bl,
                                        unsigned short* hsm, int wave, int i16, int q4, int lane)
{
    char* base = (char*)hsm;
    #pragma unroll
    for (int j = 0; j < 4; ++j) {
        int col = (wave * 4 + j) * 16 + i16;
        float bb = bl[col];
        #pragma unroll
        for (int mt = 0; mt < 4; ++mt) {
            #pragma unroll
            for (int r = 0; r < 4; ++r) {
                int row = mt * 16 + q4 * 4 + r;
                float v = fmaxf(acc[mt][j][r] + bb, 0.f);
                unsigned hv = f2bf(v);
                // quad_perm [1,0,3,2]: each lane gets partner (lane^1)'s value
                unsigned sw = (unsigned)__builtin_amdgcn_update_dpp(0, (int)hv, 0xB1, 0xF, 0xF, true);
                if ((lane & 1) == 0) {
                    int g = (col >> 3) ^ (row & 7);
                    *(unsigned*)(base + row * 1024 + g * 16 + ((col & 7) << 1)) = hv | (sw << 16);
                }
            }
        }
    }
}

// ---------------- fused layers 0..3 ----------------
// One block per (b,p): 64 pair-rows. h tile 64x512 bf16 in LDS, XOR-swizzled
// 16B granules: (row,k) at row*512 + ((k>>3)^(row&7))*8 + (k&7).
// 8 waves; wave w computes cols [w*64, w*64+64): acc = 4 (row tiles) x 4 (col tiles).
__global__ __launch_bounds__(512, 4) void k_fused(
    const float* __restrict__ x,
    const unsigned short* __restrict__ Wp,
    const unsigned short* __restrict__ W0p,
    const float* __restrict__ b0, const float* __restrict__ b1,
    const float* __restrict__ b2, const float* __restrict__ b3,
    float* __restrict__ S)
{
    __shared__ unsigned short hsm[64 * 512];   // 64 KiB
    __shared__ unsigned short xs[64 * 64];     // 8 KiB (x-pair tile, K padded to 64)
    int t = threadIdx.x;
    int blk = blockIdx.x;
    int b = blk >> 6, p = blk & 63;

    // ---- stage xs[row][k] = [x[b,row,0:26] | x[b,p,0:26] | 0...] bf16, swizzled ----
    {
        int row = t >> 3, gr = t & 7;
        const float* xq = x + (size_t)(b * 64 + row) * 26;
        const float* xp = x + (size_t)(b * 64 + p) * 26;
        unsigned w[4];
        #pragma unroll
        for (int h = 0; h < 4; ++h) {
            int k0 = gr * 8 + h * 2;
            int k1 = k0 + 1;
            float f0 = (k0 < 26) ? xq[k0] : (k0 < 52 ? xp[k0 - 26] : 0.f);
            float f1 = (k1 < 26) ? xq[k1] : (k1 < 52 ? xp[k1 - 26] : 0.f);
            w[h] = (unsigned)f2bf(f0) | ((unsigned)f2bf(f1) << 16);
        }
        int g = gr ^ (row & 7);
        *(u32x4*)((char*)xs + row * 128 + g * 16) = (u32x4){w[0], w[1], w[2], w[3]};
    }

    int wave = t >> 6, lane = t & 63;
    int i16 = lane & 15, q4 = lane >> 4, x7 = i16 & 7;

    f32x4 acc[4][4];

    __syncthreads();   // xs ready

    // ---- layer 0: h0 = relu([x_q|x_p] @ W0^T + b0), K=64 padded ----
    {
        #pragma unroll
        for (int mt = 0; mt < 4; ++mt)
            #pragma unroll
            for (int j = 0; j < 4; ++j)
                acc[mt][j] = (f32x4){0.f, 0.f, 0.f, 0.f};
        const unsigned short* Bb0 = W0p + wave * 4096 + lane * 8;
        const unsigned short* As = xs + i16 * 64;
        #pragma unroll
        for (int s = 0; s < 2; ++s) {
            bf16x8 bfr[4];
            #pragma unroll
            for (int j = 0; j < 4; ++j)
                bfr[j] = *(const bf16x8*)(Bb0 + s * 2048 + j * 512);
            int g = (s * 4 + q4) ^ x7;
            const unsigned short* A0 = As + g * 8;
            #pragma unroll
            for (int mt = 0; mt < 4; ++mt) {
                bf16x8 a = *(const bf16x8*)(A0 + mt * 1024);
                #pragma unroll
                for (int j = 0; j < 4; ++j)
                    acc[mt][j] = __builtin_amdgcn_mfma_f32_16x16x32_bf16(a, bfr[j], acc[mt][j], 0, 0, 0);
            }
        }
        store_h(acc, b0, hsm, wave, i16, q4, lane);   // each wave writes its own cols
    }

    // ---- layers 1..3, 2-deep pipelined on the L2 weight stream ----
    #pragma unroll 1
    for (int l = 0; l < 3; ++l) {
        const float* bl = (l == 0) ? b1 : (l == 1) ? b2 : b3;
        __syncthreads();   // h ready

        #pragma unroll
        for (int mt = 0; mt < 4; ++mt)
            #pragma unroll
            for (int j = 0; j < 4; ++j)
                acc[mt][j] = (f32x4){0.f, 0.f, 0.f, 0.f};

        // B fragments: one shared per-lane address; jj at +1024B, s at +4096B.
        const unsigned short* Bb = Wp + (size_t)l * 262144 + wave * 32768 + lane * 8;
        // A fragments: one shared LDS address; mt at +16384B.
        const unsigned short* Ab0 = &hsm[i16 * 512];

        bf16x8 bA[4], bB[4];
        #pragma unroll
        for (int j = 0; j < 4; ++j) bA[j] = *(const bf16x8*)(Bb + j * 512);

        #pragma unroll 1
        for (int s = 0; s < 16; s += 2) {
            // -- half 1: weights bA (step s); prefetch bB (step s+1) --
            int g0 = (s * 4 + q4) ^ x7;
            const unsigned short* A0 = Ab0 + g0 * 8;
            bf16x8 a0 = *(const bf16x8*)(A0);
            bf16x8 a1 = *(const bf16x8*)(A0 + 8192);
            #pragma unroll
            for (int j = 0; j < 4; ++j)
                bB[j] = *(const bf16x8*)(Bb + (s + 1) * 2048 + j * 512);
            __builtin_amdgcn_s_setprio(1);
            #pragma unroll
            for (int j = 0; j < 4; ++j)
                acc[0][j] = __builtin_amdgcn_mfma_f32_16x16x32_bf16(a0, bA[j], acc[0][j], 0, 0, 0);
            #pragma unroll
            for (int j = 0; j < 4; ++j)
                acc[1][j] = __builtin_amdgcn_mfma_f32_16x16x32_bf16(a1, bA[j], acc[1][j], 0, 0, 0);
            __builtin_amdgcn_s_setprio(0);
            bf16x8 a2 = *(const bf16x8*)(A0 + 16384);
            bf16x8 a3 = *(const bf16x8*)(A0 + 24576);
            __builtin_amdgcn_s_setprio(1);
            #pragma unroll
            for (int j = 0; j < 4; ++j)
                acc[2][j] = __builtin_amdgcn_mfma_f32_16x16x32_bf16(a2, bA[j], acc[2][j], 0, 0, 0);
            #pragma unroll
            for (int j = 0; j < 4; ++j)
                acc[3][j] = __builtin_amdgcn_mfma_f32_16x16x32_bf16(a3, bA[j], acc[3][j], 0, 0, 0);
            __builtin_amdgcn_s_setprio(0);

            // -- half 2: weights bB (step s+1); prefetch bA (step s+2, clamped) --
            int s2 = (s + 2 < 16) ? (s + 2) : 15;   // tail reload is harmless/unused
            int g1 = ((s + 1) * 4 + q4) ^ x7;
            const unsigned short* A1 = Ab0 + g1 * 8;
            bf16x8 c0 = *(const bf16x8*)(A1);
            bf16x8 c1 = *(const bf16x8*)(A1 + 8192);
            #pragma unroll
            for (int j = 0; j < 4; ++j)
                bA[j] = *(const bf16x8*)(Bb + s2 * 2048 + j * 512);
            __builtin_amdgcn_s_setprio(1);
            #pragma unroll
            for (int j = 0; j < 4; ++j)
                acc[0][j] = __builtin_amdgcn_mfma_f32_16x16x32_bf16(c0, bB[j], acc[0][j], 0, 0, 0);
            #pragma unroll
            for (int j = 0; j < 4; ++j)
                acc[1][j] = __builtin_amdgcn_mfma_f32_16x16x32_bf16(c1, bB[j], acc[1][j], 0, 0, 0);
            __builtin_amdgcn_s_setprio(0);
            bf16x8 c2 = *(const bf16x8*)(A1 + 16384);
            bf16x8 c3 = *(const bf16x8*)(A1 + 24576);
            __builtin_amdgcn_s_setprio(1);
            #pragma unroll
            for (int j = 0; j < 4; ++j)
                acc[2][j] = __builtin_amdgcn_mfma_f32_16x16x32_bf16(c2, bB[j], acc[2][j], 0, 0, 0);
            #pragma unroll
            for (int j = 0; j < 4; ++j)
                acc[3][j] = __builtin_amdgcn_mfma_f32_16x16x32_bf16(c3, bB[j], acc[3][j], 0, 0, 0);
            __builtin_amdgcn_s_setprio(0);
        }
        __syncthreads();   // all reads of h done before overwrite

        if (l < 2) {
            store_h(acc, bl, hsm, wave, i16, q4, lane);
        } else {
            // layer 3: bias + relu + sum over 64 rows -> atomic partial into S[b][col]
            #pragma unroll
            for (int j = 0; j < 4; ++j) {
                int col = (wave * 4 + j) * 16 + i16;
                float bb = bl[col];
                float sum = 0.f;
                #pragma unroll
                for (int mt = 0; mt < 4; ++mt)
                    #pragma unroll
                    for (int r = 0; r < 4; ++r)
                        sum += fmaxf(acc[mt][j][r] + bb, 0.f);
                sum += __shfl_xor(sum, 16);
                sum += __shfl_xor(sum, 32);
                if (q4 == 0) atomicAdd(&S[b * 512 + col], sum);
            }
        }
    }
}

// ---------------- tail: layers 4,5,6 + log_softmax (one block per batch) ----
__global__ __launch_bounds__(512) void k_tail(
    const float* __restrict__ S, const float* __restrict__ qst,
    const float* __restrict__ W4t, const float* __restrict__ b4,
    const float* __restrict__ W5t, const float* __restrict__ b5,
    const float* __restrict__ W6, const float* __restrict__ b6,
    float* __restrict__ out)
{
    int b = blockIdx.x, t = threadIdx.x;
    __shared__ float z[768];
    __shared__ float h4[512];
    __shared__ float h5[512];
    __shared__ float logits[28];
    __shared__ float red[2];

    for (int i = t; i < 768; i += 512)
        z[i] = (i < 512) ? S[b * 512 + i] : qst[b * 256 + (i - 512)];
    __syncthreads();
    {   // layer 4: 768 -> 512, relu
        float acc = b4[t];
        for (int k = 0; k < 768; ++k) acc = fmaf(W4t[k * 512 + t], z[k], acc);
        h4[t] = fmaxf(acc, 0.f);
    }
    __syncthreads();
    {   // layer 5: 512 -> 512, relu
        float acc = b5[t];
        for (int k = 0; k < 512; ++k) acc = fmaf(W5t[k * 512 + t], h4[k], acc);
        h5[t] = fmaxf(acc, 0.f);
    }
    __syncthreads();
    {   // layer 6: 512 -> 28 (16 lanes per output)
        int o = t >> 4, c = t & 15;
        if (o < 28) {
            float acc = 0.f;
            for (int k = c; k < 512; k += 16) acc = fmaf(W6[o * 512 + k], h5[k], acc);
            acc += __shfl_xor(acc, 1);
            acc += __shfl_xor(acc, 2);
            acc += __shfl_xor(acc, 4);
            acc += __shfl_xor(acc, 8);
            if (c == 0) logits[o] = acc + b6[o];
        }
    }
    __syncthreads();
    if (t == 0) {
        float mx = -1e30f;
        for (int cc = 0; cc < 28; ++cc) mx = fmaxf(mx, logits[cc]);
        float se = 0.f;
        for (int cc = 0; cc < 28; ++cc) se += expf(logits[cc] - mx);
        red[0] = mx; red[1] = logf(se);
    }
    __syncthreads();
    if (t < 28) out[b * 28 + t] = logits[t] - red[0] - red[1];
}

extern "C" void kernel_launch(void* const* d_in, const int* in_sizes, int n_in,
                              void* d_out, int out_size, void* d_ws, size_t ws_size,
                              hipStream_t stream)
{
    const float* x   = (const float*)d_in[0];
    const float* qst = (const float*)d_in[1];
    const float* W0  = (const float*)d_in[2];
    const float* b0  = (const float*)d_in[3];
    const float* W1  = (const float*)d_in[4];
    const float* b1  = (const float*)d_in[5];
    const float* W2  = (const float*)d_in[6];
    const float* b2  = (const float*)d_in[7];
    const float* W3  = (const float*)d_in[8];
    const float* b3  = (const float*)d_in[9];
    const float* W4  = (const float*)d_in[10];
    const float* b4  = (const float*)d_in[11];
    const float* W5  = (const float*)d_in[12];
    const float* b5  = (const float*)d_in[13];
    const float* W6  = (const float*)d_in[14];
    const float* b6  = (const float*)d_in[15];
    float* out = (float*)d_out;

    char* ws = (char*)d_ws;
    unsigned short* Wp  = (unsigned short*)(ws);             // 1.5 MiB
    unsigned short* W0p = (unsigned short*)(ws + 1572864);   // 64 KiB
    float*          W4t = (float*)(ws + 1638400);            // 1.5 MiB
    float*          W5t = (float*)(ws + 3211264);            // 1 MiB
    float*          S   = (float*)(ws + 4259840);            // 64 KiB

    k_prep <<<NP_TOTAL / 256, 256, 0, stream>>>(W1, W2, W3, W0, W4, W5,
                                                Wp, W0p, W4t, W5t, S);
    k_fused<<<2048, 512, 0, stream>>>(x, Wp, W0p, b0, b1, b2, b3, S);
    k_tail <<<32, 512, 0, stream>>>(S, qst, W4t, b4, W5t, b5, W6, b6, out);
}

// Round 2
// 370.336 us; speedup vs baseline: 1.2496x; 1.2496x over previous
//
#include <hip/hip_runtime.h>
#include <math.h>

// Relational Network fused pipeline for MI355X (gfx950).
// B=32, D=64, K=26, QST=256, G=[512x6, 28], AGG at layer 4.
//
// Round 7 changes vs round 6:
//  - Reverted the B ping-pong (it spilled 256 B/thread -> 268 MB scratch,
//    thrashing L3). Single bfr[4] per s-step, A-frags loaded in mt-pairs.
//    Live set ~100 regs < 128 unified cap at launch_bounds(512,4).
//  - New LDS layout for h: granule-column-major hsm[g=k>>3][slot=row^(g&7)][8].
//    A-read per (s,mt) is now 4 contiguous-permuted 256B chunks (lanes 0-15
//    in one 256B range) -> conflict-free b128 (round5/6 layout was 8-way:
//    1.26e7 conflict cycles, all from A-reads). One per-lane base, immediate
//    offsets s*4096 + mt*256.
//  - k_tail: W4/W5 repacked [k/4][512][float4]; per-thread float4 weight
//    stream (4x fewer VMEM issues), identical accumulation order.

typedef __attribute__((ext_vector_type(8))) short bf16x8;   // 8 bf16 in 4 VGPRs
typedef __attribute__((ext_vector_type(4))) float f32x4;    // MFMA 16x16 accumulator
typedef __attribute__((ext_vector_type(4))) unsigned int u32x4;

__device__ __forceinline__ unsigned short f2bf(float f) {
    union { float f; unsigned u; } x; x.f = f;
    unsigned r = x.u + 0x7fffu + ((x.u >> 16) & 1u);   // RNE
    return (unsigned short)(r >> 16);
}

// ---------------- pack / transpose weights (+ zero S) ----------------
// Wp layout per layer: [wave(8)][s(16)][jj(4)][lane(64)][j(8)] bf16,
//   value = W[n][k], n = (wave*4+jj)*16 + (lane&15), k = s*32 + (lane>>4)*8 + j.
// W0p: same with s(2) over padded K=64 (k >= 52 -> 0).
// W4v/W5v: fp32 [k/4][512 out][4] so k_tail threads stream float4.
#define NP_WP   786432            // 3 * 512*512
#define NP_W0P  32768             // 512*64 (K padded 52->64)
#define NP_W4T  393216            // 512*768
#define NP_W5T  262144            // 512*512
#define NP_S    16384             // 32*512
#define NP_TOTAL (NP_WP + NP_W0P + NP_W4T + NP_W5T + NP_S)
__global__ void k_prep(const float* __restrict__ W1, const float* __restrict__ W2,
                       const float* __restrict__ W3, const float* __restrict__ W0,
                       const float* __restrict__ W4, const float* __restrict__ W5,
                       unsigned short* __restrict__ Wp,   // [3][262144] bf16
                       unsigned short* __restrict__ W0p,  // [32768] bf16
                       float* __restrict__ W4v,           // [192][512][4] fp32
                       float* __restrict__ W5v,           // [128][512][4] fp32
                       float* __restrict__ S)             // [32][512] fp32 (zeroed)
{
    int f = blockIdx.x * 256 + threadIdx.x;
    if (f < NP_WP) {
        int l = f >> 18, r = f & 262143;
        int n = r >> 9, k = r & 511;                    // read W[n*512+k] coalesced
        const float* W = (l == 0) ? W1 : (l == 1) ? W2 : W3;
        float v = W[r];
        int wv = n >> 6, jj = (n >> 4) & 3, i16 = n & 15;
        int s = k >> 5, q4 = (k >> 3) & 3, j = k & 7;
        int lane = q4 * 16 + i16;
        Wp[(size_t)l * 262144 + ((((wv * 16 + s) * 4 + jj) * 64 + lane) << 3) + j] = f2bf(v);
    } else if (f < NP_WP + NP_W0P) {
        int g = f - NP_WP;
        int n = g >> 6, k = g & 63;
        float v = (k < 52) ? W0[n * 52 + k] : 0.f;
        int wv = n >> 6, jj = (n >> 4) & 3, i16 = n & 15;
        int s = k >> 5, q4 = (k >> 3) & 3, j = k & 7;
        int lane = q4 * 16 + i16;
        W0p[((((wv * 2 + s) * 4 + jj) * 64 + lane) << 3) + j] = f2bf(v);
    } else if (f < NP_WP + NP_W0P + NP_W4T) {
        int g = f - (NP_WP + NP_W0P);
        int o = g / 768, k = g % 768;                   // read W4[g] coalesced
        W4v[(size_t)((k >> 2) * 512 + o) * 4 + (k & 3)] = W4[g];
    } else if (f < NP_WP + NP_W0P + NP_W4T + NP_W5T) {
        int g = f - (NP_WP + NP_W0P + NP_W4T);
        int o = g >> 9, k = g & 511;                    // read W5[g] coalesced
        W5v[(size_t)((k >> 2) * 512 + o) * 4 + (k & 3)] = W5[g];
    } else if (f < NP_TOTAL) {
        S[f - (NP_WP + NP_W0P + NP_W4T + NP_W5T)] = 0.f;
    }
}

// ---------------- h-store epilogue: bias + relu + bf16 LDS write ----
// Granule-column-major target: byte = (col>>3)*1024 + (row ^ ((col>>3)&7))*16
//                                    + (col&7)*2.
// Packs (col, col+1) via DPP quad_perm; even lanes write ds_write_b32.
__device__ __forceinline__ void store_h(const f32x4 (&acc)[4][4], const float* __restrict__ bl,
                                        unsigned short* hsm, int wave, int i16, int q4, int lane)
{
    char* base = (char*)hsm;
    #pragma unroll
    for (int j = 0; j < 4; ++j) {
        int col = (wave * 4 + j) * 16 + i16;
        int g = col >> 3;
        int e = g & 7;
        float bb = bl[col];
        #pragma unroll
        for (int mt = 0; mt < 4; ++mt) {
            #pragma unroll
            for (int r = 0; r < 4; ++r) {
                int row = mt * 16 + q4 * 4 + r;
                float v = fmaxf(acc[mt][j][r] + bb, 0.f);
                unsigned hv = f2bf(v);
                // quad_perm [1,0,3,2]: each lane gets partner (lane^1)'s value
                unsigned sw = (unsigned)__builtin_amdgcn_update_dpp(0, (int)hv, 0xB1, 0xF, 0xF, true);
                if ((lane & 1) == 0) {
                    int slot = row ^ e;
                    *(unsigned*)(base + g * 1024 + slot * 16 + ((col & 7) << 1)) = hv | (sw << 16);
                }
            }
        }
    }
}

// ---------------- fused layers 0..3 ----------------
// One block per (b,p): 64 pair-rows. h tile 64x512 bf16 in LDS,
// granule-column-major: hsm[g=k>>3][slot=row^(g&7)][8 shorts].
// 8 waves; wave w computes cols [w*64, w*64+64): acc = 4 (row tiles) x 4 (col tiles).
__global__ __launch_bounds__(512, 4) void k_fused(
    const float* __restrict__ x,
    const unsigned short* __restrict__ Wp,
    const unsigned short* __restrict__ W0p,
    const float* __restrict__ b0, const float* __restrict__ b1,
    const float* __restrict__ b2, const float* __restrict__ b3,
    float* __restrict__ S)
{
    __shared__ __align__(16) unsigned short hsm[64 * 512];   // 64 KiB
    __shared__ __align__(16) unsigned short xs[8 * 64 * 8];  // 8 KiB (x-pair tile)
    int t = threadIdx.x;
    int blk = blockIdx.x;
    int b = blk >> 6, p = blk & 63;

    // ---- stage xs: [g(8)][slot=row^g][8] bf16 of [x[b,row,:26] | x[b,p,:26] | 0] ----
    {
        int row = t >> 3, gr = t & 7;
        const float* xq = x + (size_t)(b * 64 + row) * 26;
        const float* xp = x + (size_t)(b * 64 + p) * 26;
        unsigned w[4];
        #pragma unroll
        for (int h = 0; h < 4; ++h) {
            int k0 = gr * 8 + h * 2;
            int k1 = k0 + 1;
            float f0 = (k0 < 26) ? xq[k0] : (k0 < 52 ? xp[k0 - 26] : 0.f);
            float f1 = (k1 < 26) ? xq[k1] : (k1 < 52 ? xp[k1 - 26] : 0.f);
            w[h] = (unsigned)f2bf(f0) | ((unsigned)f2bf(f1) << 16);
        }
        *(u32x4*)((char*)xs + gr * 1024 + ((row ^ gr) << 4)) = (u32x4){w[0], w[1], w[2], w[3]};
    }

    int wave = t >> 6, lane = t & 63;
    int i16 = lane & 15, q4 = lane >> 4;

    f32x4 acc[4][4];

    __syncthreads();   // xs ready

    // ---- layer 0: h0 = relu([x_q|x_p] @ W0^T + b0), K=64 padded ----
    {
        #pragma unroll
        for (int mt = 0; mt < 4; ++mt)
            #pragma unroll
            for (int j = 0; j < 4; ++j)
                acc[mt][j] = (f32x4){0.f, 0.f, 0.f, 0.f};
        const unsigned short* Bb0 = W0p + wave * 4096 + lane * 8;
        const char* xb = (const char*)xs;
        #pragma unroll
        for (int s = 0; s < 2; ++s) {
            bf16x8 bfr[4];
            #pragma unroll
            for (int j = 0; j < 4; ++j)
                bfr[j] = *(const bf16x8*)(Bb0 + s * 2048 + j * 512);
            int g = s * 4 + q4;
            const char* A0 = xb + g * 1024 + ((i16 ^ g) << 4);
            #pragma unroll
            for (int mt = 0; mt < 4; ++mt) {
                bf16x8 a = *(const bf16x8*)(A0 + mt * 256);
                #pragma unroll
                for (int j = 0; j < 4; ++j)
                    acc[mt][j] = __builtin_amdgcn_mfma_f32_16x16x32_bf16(a, bfr[j], acc[mt][j], 0, 0, 0);
            }
        }
        store_h(acc, b0, hsm, wave, i16, q4, lane);   // each wave writes its own cols
    }

    // ---- layers 1..3 ----
    // A-read byte addr: (s*4+q4)*1024 + mt*256 + ((i16 ^ (q4 + 4*(s&1)))<<4)
    //                 = s*4096 + A_base(s&1) + mt*256.
    int A_even = (q4 << 10) + ((i16 ^ q4) << 4);
    int A_odd  = A_even ^ 64;
    const char* hb = (const char*)hsm;

    #pragma unroll 1
    for (int l = 0; l < 3; ++l) {
        const float* bl = (l == 0) ? b1 : (l == 1) ? b2 : b3;
        __syncthreads();   // h ready

        #pragma unroll
        for (int mt = 0; mt < 4; ++mt)
            #pragma unroll
            for (int j = 0; j < 4; ++j)
                acc[mt][j] = (f32x4){0.f, 0.f, 0.f, 0.f};

        // B fragments: one shared per-lane address; jj at +1024B, s at +4096B.
        const unsigned short* Bb = Wp + (size_t)l * 262144 + wave * 32768 + lane * 8;

        #pragma unroll 1
        for (int s = 0; s < 16; ++s) {
            bf16x8 bfr[4];
            #pragma unroll
            for (int j = 0; j < 4; ++j)
                bfr[j] = *(const bf16x8*)(Bb + s * 2048 + j * 512);
            const char* Ab = hb + (s << 12) + ((s & 1) ? A_odd : A_even);
            bf16x8 a0 = *(const bf16x8*)(Ab);
            bf16x8 a1 = *(const bf16x8*)(Ab + 256);
            __builtin_amdgcn_s_setprio(1);
            #pragma unroll
            for (int j = 0; j < 4; ++j)
                acc[0][j] = __builtin_amdgcn_mfma_f32_16x16x32_bf16(a0, bfr[j], acc[0][j], 0, 0, 0);
            #pragma unroll
            for (int j = 0; j < 4; ++j)
                acc[1][j] = __builtin_amdgcn_mfma_f32_16x16x32_bf16(a1, bfr[j], acc[1][j], 0, 0, 0);
            __builtin_amdgcn_s_setprio(0);
            bf16x8 a2 = *(const bf16x8*)(Ab + 512);
            bf16x8 a3 = *(const bf16x8*)(Ab + 768);
            __builtin_amdgcn_s_setprio(1);
            #pragma unroll
            for (int j = 0; j < 4; ++j)
                acc[2][j] = __builtin_amdgcn_mfma_f32_16x16x32_bf16(a2, bfr[j], acc[2][j], 0, 0, 0);
            #pragma unroll
            for (int j = 0; j < 4; ++j)
                acc[3][j] = __builtin_amdgcn_mfma_f32_16x16x32_bf16(a3, bfr[j], acc[3][j], 0, 0, 0);
            __builtin_amdgcn_s_setprio(0);
        }
        __syncthreads();   // all reads of h done before overwrite

        if (l < 2) {
            store_h(acc, bl, hsm, wave, i16, q4, lane);
        } else {
            // layer 3: bias + relu + sum over 64 rows -> atomic partial into S[b][col]
            #pragma unroll
            for (int j = 0; j < 4; ++j) {
                int col = (wave * 4 + j) * 16 + i16;
                float bb = bl[col];
                float sum = 0.f;
                #pragma unroll
                for (int mt = 0; mt < 4; ++mt)
                    #pragma unroll
                    for (int r = 0; r < 4; ++r)
                        sum += fmaxf(acc[mt][j][r] + bb, 0.f);
                sum += __shfl_xor(sum, 16);
                sum += __shfl_xor(sum, 32);
                if (q4 == 0) atomicAdd(&S[b * 512 + col], sum);
            }
        }
    }
}

// ---------------- tail: layers 4,5,6 + log_softmax (one block per batch) ----
__global__ __launch_bounds__(512) void k_tail(
    const float* __restrict__ S, const float* __restrict__ qst,
    const float* __restrict__ W4v, const float* __restrict__ b4,
    const float* __restrict__ W5v, const float* __restrict__ b5,
    const float* __restrict__ W6, const float* __restrict__ b6,
    float* __restrict__ out)
{
    int b = blockIdx.x, t = threadIdx.x;
    __shared__ __align__(16) float z[768];
    __shared__ __align__(16) float h4[512];
    __shared__ float h5[512];
    __shared__ float logits[28];
    __shared__ float red[2];

    for (int i = t; i < 768; i += 512)
        z[i] = (i < 512) ? S[b * 512 + i] : qst[b * 256 + (i - 512)];
    __syncthreads();
    {   // layer 4: 768 -> 512, relu (float4 weight stream, k-ascending order)
        float acc = b4[t];
        const float4* Wv = (const float4*)W4v;
        const float4* z4 = (const float4*)z;
        #pragma unroll 4
        for (int kb = 0; kb < 192; ++kb) {
            float4 w = Wv[kb * 512 + t];
            float4 zz = z4[kb];
            acc = fmaf(w.x, zz.x, acc);
            acc = fmaf(w.y, zz.y, acc);
            acc = fmaf(w.z, zz.z, acc);
            acc = fmaf(w.w, zz.w, acc);
        }
        h4[t] = fmaxf(acc, 0.f);
    }
    __syncthreads();
    {   // layer 5: 512 -> 512, relu
        float acc = b5[t];
        const float4* Wv = (const float4*)W5v;
        const float4* h44 = (const float4*)h4;
        #pragma unroll 4
        for (int kb = 0; kb < 128; ++kb) {
            float4 w = Wv[kb * 512 + t];
            float4 hh = h44[kb];
            acc = fmaf(w.x, hh.x, acc);
            acc = fmaf(w.y, hh.y, acc);
            acc = fmaf(w.z, hh.z, acc);
            acc = fmaf(w.w, hh.w, acc);
        }
        h5[t] = fmaxf(acc, 0.f);
    }
    __syncthreads();
    {   // layer 6: 512 -> 28 (16 lanes per output)
        int o = t >> 4, c = t & 15;
        if (o < 28) {
            float acc = 0.f;
            for (int k = c; k < 512; k += 16) acc = fmaf(W6[o * 512 + k], h5[k], acc);
            acc += __shfl_xor(acc, 1);
            acc += __shfl_xor(acc, 2);
            acc += __shfl_xor(acc, 4);
            acc += __shfl_xor(acc, 8);
            if (c == 0) logits[o] = acc + b6[o];
        }
    }
    __syncthreads();
    if (t == 0) {
        float mx = -1e30f;
        for (int cc = 0; cc < 28; ++cc) mx = fmaxf(mx, logits[cc]);
        float se = 0.f;
        for (int cc = 0; cc < 28; ++cc) se += expf(logits[cc] - mx);
        red[0] = mx; red[1] = logf(se);
    }
    __syncthreads();
    if (t < 28) out[b * 28 + t] = logits[t] - red[0] - red[1];
}

extern "C" void kernel_launch(void* const* d_in, const int* in_sizes, int n_in,
                              void* d_out, int out_size, void* d_ws, size_t ws_size,
                              hipStream_t stream)
{
    const float* x   = (const float*)d_in[0];
    const float* qst = (const float*)d_in[1];
    const float* W0  = (const float*)d_in[2];
    const float* b0  = (const float*)d_in[3];
    const float* W1  = (const float*)d_in[4];
    const float* b1  = (const float*)d_in[5];
    const float* W2  = (const float*)d_in[6];
    const float* b2  = (const float*)d_in[7];
    const float* W3  = (const float*)d_in[8];
    const float* b3  = (const float*)d_in[9];
    const float* W4  = (const float*)d_in[10];
    const float* b4  = (const float*)d_in[11];
    const float* W5  = (const float*)d_in[12];
    const float* b5  = (const float*)d_in[13];
    const float* W6  = (const float*)d_in[14];
    const float* b6  = (const float*)d_in[15];
    float* out = (float*)d_out;

    char* ws = (char*)d_ws;
    unsigned short* Wp  = (unsigned short*)(ws);             // 1.5 MiB
    unsigned short* W0p = (unsigned short*)(ws + 1572864);   // 64 KiB
    float*          W4v = (float*)(ws + 1638400);            // 1.5 MiB
    float*          W5v = (float*)(ws + 3211264);            // 1 MiB
    float*          S   = (float*)(ws + 4259840);            // 64 KiB

    k_prep <<<NP_TOTAL / 256, 256, 0, stream>>>(W1, W2, W3, W0, W4, W5,
                                                Wp, W0p, W4v, W5v, S);
    k_fused<<<2048, 512, 0, stream>>>(x, Wp, W0p, b0, b1, b2, b3, S);
    k_tail <<<32, 512, 0, stream>>>(S, qst, W4v, b4, W5v, b5, W6, b6, out);
}